// Round 2
// baseline (923.549 us; speedup 1.0000x reference)
//
#include <hip/hip_runtime.h>

typedef unsigned short ushort_t;
typedef __attribute__((ext_vector_type(8))) short short8;
typedef __attribute__((ext_vector_type(4))) short s16x4;
typedef __attribute__((ext_vector_type(4))) float f32x4;

#define LN_EPS 1e-5f

// LDS layout (bytes), time-multiplexed (barriers separate lifetimes):
//  P0-P1 : xw f32  [64][132]   @0      (33792)  XOR-swizzled cols (bits2-3 ^= row bits3-4)
//  P1-P2 : xn bf16 [64][136]   @33792  (17408, ends 51200)
//  P2-P3 : q  bf16 [4][64][32] @0      (16384)  XOR swz: d ^= (row&3)<<3
//          k  bf16 [4][64][32] @16384  (16384)  same swz
//  P2-P4 : vT bf16 [4][32][72] @32768  (18432, ends 51200)
//  P3-P4 : p  bf16 [4][64][64] @0      (32768)  XOR swz: col ^= (row&7)<<3   (aliases q+k exactly)
//  P4-P5 : o  bf16 [64][136]   @0      (17408)
//  P5-P6 : y  bf16 [64][136]   @17408  (17408)
// Peak = 51200 B -> 3 blocks/CU (160K/51200 = 3.2).
#define XW_OFF 0
#define XN_OFF 33792
#define Q_OFF  0
#define K_OFF  16384
#define V_OFF  32768
#define P_OFF  0
#define O_OFF  0
#define Y_OFF  17408
#define SMEM_BYTES 51200

// bf16 weight workspace layout (shorts): wq [384*128] @0, wo @49152, wc @65536; 81920 shorts = 163840 B
#define WS_NEED 163840

static __device__ __forceinline__ ushort_t f2bf(float f) {
    union { float f; unsigned int u; } cv; cv.f = f;
    unsigned int x = cv.u + 0x7FFFu + ((cv.u >> 16) & 1u);   // RNE
    return (ushort_t)(x >> 16);
}

static __device__ __forceinline__ short8 loadw8(const float* p) {  // 8 f32 -> 8 bf16
    float4 a = *(const float4*)p;
    float4 b = *(const float4*)(p + 4);
    short8 r;
    r[0] = (short)f2bf(a.x); r[1] = (short)f2bf(a.y); r[2] = (short)f2bf(a.z); r[3] = (short)f2bf(a.w);
    r[4] = (short)f2bf(b.x); r[5] = (short)f2bf(b.y); r[6] = (short)f2bf(b.z); r[7] = (short)f2bf(b.w);
    return r;
}

// q/k LDS index: [h][row 0..63][d 0..31], stride 32 shorts (64B rows), bank-swizzled
static __device__ __forceinline__ int qk_i(int row, int d) {
    return row * 32 + (d ^ ((row & 3) << 3));
}
// p LDS index: [h][row 0..63][col 0..63], stride 64 shorts (128B rows), bank-swizzled
static __device__ __forceinline__ int p_i(int row, int col) {
    return row * 64 + (col ^ ((row & 7) << 3));
}

__global__ void wconv_kernel(const float* __restrict__ wq, const float* __restrict__ wo,
                             const float* __restrict__ wc, ushort_t* __restrict__ ws) {
    int i = blockIdx.x * 256 + threadIdx.x;   // 20480 threads x 4 floats
    float4 v;
    if (i < 12288)      v = ((const float4*)wq)[i];
    else if (i < 16384) v = ((const float4*)wo)[i - 12288];
    else                v = ((const float4*)wc)[i - 16384];
    s16x4 s;
    s[0] = (short)f2bf(v.x); s[1] = (short)f2bf(v.y);
    s[2] = (short)f2bf(v.z); s[3] = (short)f2bf(v.w);
    *(s16x4*)(ws + i * 4) = s;
}

template <bool PRE>
__global__ __launch_bounds__(512, 6) void wattn_kernel(
    const float* __restrict__ x,
    const float* __restrict__ ln_g,
    const float* __restrict__ ln_b,
    const float* __restrict__ w_qkv,   // [384][128] row-major (o,c)
    const float* __restrict__ b_qkv,
    const float* __restrict__ w_out,   // [128][128]
    const float* __restrict__ b_out,
    const float* __restrict__ w_cv,    // [128][128]
    const float* __restrict__ b_cv,
    const ushort_t* __restrict__ wbf,  // preconverted bf16 weights (if PRE)
    float* __restrict__ out)
{
    extern __shared__ char smem[];
    float*    xw  = (float*)(smem + XW_OFF);      // [64][132] f32, swizzled
    ushort_t* xn  = (ushort_t*)(smem + XN_OFF);   // [64][136]
    ushort_t* qls = (ushort_t*)(smem + Q_OFF);    // [4][64][32] swz
    ushort_t* kls = (ushort_t*)(smem + K_OFF);    // [4][64][32] swz
    ushort_t* vls = (ushort_t*)(smem + V_OFF);    // [4][32][72]
    ushort_t* pls = (ushort_t*)(smem + P_OFF);    // [4][64][64] swz, alias q/k
    ushort_t* ols = (ushort_t*)(smem + O_OFF);    // [64][136]   alias p
    ushort_t* yls = (ushort_t*)(smem + Y_OFF);    // [64][136]

    const int tid  = threadIdx.x;
    const int lane = tid & 63;
    const int wv   = tid >> 6;
    const int l15  = lane & 15;
    const int quad = lane >> 4;

    // XCD-aware bijective swizzle (8192 % 8 == 0)
    const int win = (blockIdx.x & 7) * 1024 + (blockIdx.x >> 3);
    const int bN  = win >> 12;
    const int dz  = (win >> 8) & 15;
    const int hy  = (win >> 4) & 15;
    const int wx  = win & 15;
    const long base = ((long)(bN * 128) * 64 + dz * 4) * 4096 + (long)(hy * 4) * 64 + wx * 4;

    // ---------- Phase 0: gather window -> xw[t][c^sw]  (float4 along W) ----------
    // bank = 16*(th&1) + 4*i + (tid>>4) + 4*(th>>1) + 8*(td&1) : bijective -> conflict-free
    #pragma unroll
    for (int j = 0; j < 4; ++j) {
        int i  = tid + j * 512;      // [c:128][td:4][th:4]
        int c  = i >> 4;
        int td = (i >> 2) & 3;
        int th = i & 3;
        float4 v = *(const float4*)(x + base + (long)c * 262144 + td * 4096 + th * 64);
        int t0 = td * 16 + th * 4;
        int cs = c ^ ((th >> 1) << 2) ^ ((td & 1) << 3);   // == c ^ ((t>>3&1)<<2) ^ ((t>>4&1)<<3)
        xw[(t0 + 0) * 132 + cs] = v.x;
        xw[(t0 + 1) * 132 + cs] = v.y;
        xw[(t0 + 2) * 132 + cs] = v.z;
        xw[(t0 + 3) * 132 + cs] = v.w;
    }
    __syncthreads();

    // ---------- Phase 1: LayerNorm over channels -> xn (bf16, short8 stores) ----------
    {
        int t = tid >> 3;            // token, 8 threads/token
        int p = tid & 7;
        int sw = (((t >> 3) & 1) << 2) | (((t >> 4) & 1) << 3);   // wave-uniform
        float vals[16];
        #pragma unroll
        for (int m = 0; m < 4; ++m) {
            float4 v = *(const float4*)(xw + t * 132 + p * 16 + ((4 * m) ^ sw));
            vals[4 * m + 0] = v.x; vals[4 * m + 1] = v.y;
            vals[4 * m + 2] = v.z; vals[4 * m + 3] = v.w;
        }
        float s = 0.f, ss = 0.f;
        #pragma unroll
        for (int j = 0; j < 16; ++j) { s += vals[j]; ss += vals[j] * vals[j]; }
        #pragma unroll
        for (int off = 1; off < 8; off <<= 1) {
            s  += __shfl_xor(s, off, 64);
            ss += __shfl_xor(ss, off, 64);
        }
        float mu   = s * 0.0078125f;
        float var  = ss * 0.0078125f - mu * mu;
        float rstd = rsqrtf(var + LN_EPS);
        const float4* gp = (const float4*)(ln_g + p * 16);
        const float4* bp = (const float4*)(ln_b + p * 16);
        float4 g0 = gp[0], g1 = gp[1], g2 = gp[2], g3 = gp[3];
        float4 b0 = bp[0], b1 = bp[1], b2 = bp[2], b3 = bp[3];
        float gv[16] = {g0.x,g0.y,g0.z,g0.w, g1.x,g1.y,g1.z,g1.w,
                        g2.x,g2.y,g2.z,g2.w, g3.x,g3.y,g3.z,g3.w};
        float bv[16] = {b0.x,b0.y,b0.z,b0.w, b1.x,b1.y,b1.z,b1.w,
                        b2.x,b2.y,b2.z,b2.w, b3.x,b3.y,b3.z,b3.w};
        short8 o0, o1;
        #pragma unroll
        for (int j = 0; j < 8; ++j)  o0[j] = (short)f2bf((vals[j]     - mu) * rstd * gv[j]     + bv[j]);
        #pragma unroll
        for (int j = 0; j < 8; ++j)  o1[j] = (short)f2bf((vals[j + 8] - mu) * rstd * gv[j + 8] + bv[j + 8]);
        *(short8*)(xn + t * 136 + p * 16)     = o0;
        *(short8*)(xn + t * 136 + p * 16 + 8) = o1;
    }
    __syncthreads();

    // ---------- Phase 2: QKV GEMM [64x128]@[128x384], wave owns 48 cols ----------
    {
        const int n_base = wv * 48;
        f32x4 acc[4][3];
        #pragma unroll
        for (int mi = 0; mi < 4; ++mi)
            #pragma unroll
            for (int ni = 0; ni < 3; ++ni) acc[mi][ni] = (f32x4){0.f, 0.f, 0.f, 0.f};
        #pragma unroll
        for (int ks = 0; ks < 4; ++ks) {
            int k0 = ks * 32 + quad * 8;
            short8 a[4], bfr[3];
            #pragma unroll
            for (int mi = 0; mi < 4; ++mi) a[mi] = *(const short8*)(xn + (mi * 16 + l15) * 136 + k0);
            #pragma unroll
            for (int ni = 0; ni < 3; ++ni) {
                if constexpr (PRE) bfr[ni] = *(const short8*)(wbf + (n_base + ni * 16 + l15) * 128 + k0);
                else               bfr[ni] = loadw8(w_qkv + (n_base + ni * 16 + l15) * 128 + k0);
            }
            #pragma unroll
            for (int ni = 0; ni < 3; ++ni)
                #pragma unroll
                for (int mi = 0; mi < 4; ++mi)
                    acc[mi][ni] = __builtin_amdgcn_mfma_f32_16x16x32_bf16(a[mi], bfr[ni], acc[mi][ni], 0, 0, 0);
        }
        __syncthreads();   // all waves done reading xn -> q/k/vT may overwrite xw/xn
        // epilogue: +bias, scatter q[h][t][d], k[h][t][d], vT[h][d][t]
        #pragma unroll
        for (int ni = 0; ni < 3; ++ni) {
            int col  = n_base + ni * 16 + l15;
            float bias = b_qkv[col];
            int sect = col >> 7;          // uniform per tile (16 | 128)
            int cc   = col & 127;
            int h = cc >> 5, d = cc & 31;
            #pragma unroll
            for (int mi = 0; mi < 4; ++mi)
                #pragma unroll
                for (int r = 0; r < 4; ++r) {
                    int row = mi * 16 + quad * 4 + r;
                    ushort_t val = f2bf(acc[mi][ni][r] + bias);
                    if (sect == 0)      qls[h * 2048 + qk_i(row, d)] = val;
                    else if (sect == 1) kls[h * 2048 + qk_i(row, d)] = val;
                    else                vls[h * 2304 + d * 72 + row] = val;
                }
        }
    }
    __syncthreads();

    // ---------- Phase 3/4: attention. wave w: head w>>1, q-rows (w&1)*32.. ----------
    {
        const int h  = wv >> 1;
        const int m0 = (wv & 1) * 32;
        const ushort_t* qh = qls + h * 2048;
        const ushort_t* kh = kls + h * 2048;
        f32x4 sc[2][4];
        #pragma unroll
        for (int mi = 0; mi < 2; ++mi)
            #pragma unroll
            for (int ni = 0; ni < 4; ++ni) sc[mi][ni] = (f32x4){0.f, 0.f, 0.f, 0.f};
        {
            short8 a[2], bfr[4];
            #pragma unroll
            for (int mi = 0; mi < 2; ++mi) a[mi] = *(const short8*)(qh + qk_i(m0 + mi * 16 + l15, quad * 8));
            #pragma unroll
            for (int ni = 0; ni < 4; ++ni) bfr[ni] = *(const short8*)(kh + qk_i(ni * 16 + l15, quad * 8));
            #pragma unroll
            for (int ni = 0; ni < 4; ++ni)
                #pragma unroll
                for (int mi = 0; mi < 2; ++mi)
                    sc[mi][ni] = __builtin_amdgcn_mfma_f32_16x16x32_bf16(a[mi], bfr[ni], sc[mi][ni], 0, 0, 0);
        }
        const float scale = 0.1767766952966369f;   // 1/sqrt(32)
        float pv[2][4][4];
        #pragma unroll
        for (int mi = 0; mi < 2; ++mi)
            #pragma unroll
            for (int r = 0; r < 4; ++r) {
                float v0 = sc[mi][0][r] * scale, v1 = sc[mi][1][r] * scale;
                float v2 = sc[mi][2][r] * scale, v3 = sc[mi][3][r] * scale;
                float mx = fmaxf(fmaxf(v0, v1), fmaxf(v2, v3));
                #pragma unroll
                for (int off = 1; off < 16; off <<= 1) mx = fmaxf(mx, __shfl_xor(mx, off, 64));
                float e0 = __expf(v0 - mx), e1 = __expf(v1 - mx), e2 = __expf(v2 - mx), e3 = __expf(v3 - mx);
                float sum = e0 + e1 + e2 + e3;
                #pragma unroll
                for (int off = 1; off < 16; off <<= 1) sum += __shfl_xor(sum, off, 64);
                float inv = 1.f / sum;
                pv[mi][0][r] = e0 * inv; pv[mi][1][r] = e1 * inv;
                pv[mi][2][r] = e2 * inv; pv[mi][3][r] = e3 * inv;
            }
        __syncthreads();   // all waves done with q/k -> safe to overlay p
        ushort_t* ph = pls + h * 4096;
        #pragma unroll
        for (int mi = 0; mi < 2; ++mi)
            #pragma unroll
            for (int ni = 0; ni < 4; ++ni)
                #pragma unroll
                for (int r = 0; r < 4; ++r)
                    ph[p_i(m0 + mi * 16 + quad * 4 + r, ni * 16 + l15)] = f2bf(pv[mi][ni][r]);
        __syncthreads();   // fence: p stores (ushort) vs short8 reloads below
        // P @ V   [32x64]@[64x32]
        f32x4 oacc[2][2];
        #pragma unroll
        for (int mi = 0; mi < 2; ++mi)
            #pragma unroll
            for (int ni = 0; ni < 2; ++ni) oacc[mi][ni] = (f32x4){0.f, 0.f, 0.f, 0.f};
        #pragma unroll
        for (int kk = 0; kk < 2; ++kk) {
            int kq = kk * 32 + quad * 8;
            short8 a[2], bfr[2];
            #pragma unroll
            for (int mi = 0; mi < 2; ++mi) a[mi] = *(const short8*)(ph + p_i(m0 + mi * 16 + l15, kq));
            #pragma unroll
            for (int ni = 0; ni < 2; ++ni) bfr[ni] = *(const short8*)(vls + h * 2304 + (ni * 16 + l15) * 72 + kq);
            #pragma unroll
            for (int ni = 0; ni < 2; ++ni)
                #pragma unroll
                for (int mi = 0; mi < 2; ++mi)
                    oacc[mi][ni] = __builtin_amdgcn_mfma_f32_16x16x32_bf16(a[mi], bfr[ni], oacc[mi][ni], 0, 0, 0);
        }
        __syncthreads();   // all waves done reading p/vT -> o may overwrite p
        #pragma unroll
        for (int mi = 0; mi < 2; ++mi)
            #pragma unroll
            for (int ni = 0; ni < 2; ++ni)
                #pragma unroll
                for (int r = 0; r < 4; ++r)
                    ols[(m0 + mi * 16 + quad * 4 + r) * 136 + h * 32 + ni * 16 + l15] = f2bf(oacc[mi][ni][r]);
    }
    __syncthreads();

    // residual: lane (col, quad, mi) needs x[t0..t0+3] at channel col — one float4
    // along W per mi, identical mapping in P5/P6. L2-hot (fetched in P0; in-flight
    // window set per XCD = 3 blk/CU * 32 CU * 32KB = 3MB < 4MB L2).
    const int n0  = wv * 16;
    const int col = n0 + l15;
    float res[4][4];
    #pragma unroll
    for (int mi = 0; mi < 4; ++mi) {
        float4 r4 = *(const float4*)(x + base + (long)col * 262144 + mi * 4096 + quad * 64);
        res[mi][0] = r4.x; res[mi][1] = r4.y; res[mi][2] = r4.z; res[mi][3] = r4.w;
    }

    // ---------- Phase 5: out_proj [64x128]@[128x128] + attn residual -> y (bf16) ----------
    {
        f32x4 acc[4];
        #pragma unroll
        for (int mi = 0; mi < 4; ++mi) acc[mi] = (f32x4){0.f, 0.f, 0.f, 0.f};
        #pragma unroll
        for (int ks = 0; ks < 4; ++ks) {
            int k0 = ks * 32 + quad * 8;
            short8 bfr;
            if constexpr (PRE) bfr = *(const short8*)(wbf + 49152 + (n0 + l15) * 128 + k0);
            else               bfr = loadw8(w_out + (n0 + l15) * 128 + k0);
            #pragma unroll
            for (int mi = 0; mi < 4; ++mi) {
                short8 a = *(const short8*)(ols + (mi * 16 + l15) * 136 + k0);
                acc[mi] = __builtin_amdgcn_mfma_f32_16x16x32_bf16(a, bfr, acc[mi], 0, 0, 0);
            }
        }
        float bias = b_out[col];
        #pragma unroll
        for (int mi = 0; mi < 4; ++mi)
            #pragma unroll
            for (int r = 0; r < 4; ++r) {
                int row = mi * 16 + quad * 4 + r;
                yls[row * 136 + col] = f2bf(acc[mi][r] + bias + res[mi][r]);
            }
    }
    __syncthreads();

    // ---------- Phase 6: conv [64x128]@[128x128] + input residual -> direct global store ----------
    {
        f32x4 acc[4];
        #pragma unroll
        for (int mi = 0; mi < 4; ++mi) acc[mi] = (f32x4){0.f, 0.f, 0.f, 0.f};
        #pragma unroll
        for (int ks = 0; ks < 4; ++ks) {
            int k0 = ks * 32 + quad * 8;
            short8 bfr;
            if constexpr (PRE) bfr = *(const short8*)(wbf + 65536 + (n0 + l15) * 128 + k0);
            else               bfr = loadw8(w_cv + (n0 + l15) * 128 + k0);
            #pragma unroll
            for (int mi = 0; mi < 4; ++mi) {
                short8 a = *(const short8*)(yls + (mi * 16 + l15) * 136 + k0);
                acc[mi] = __builtin_amdgcn_mfma_f32_16x16x32_bf16(a, bfr, acc[mi], 0, 0, 0);
            }
        }
        float bias = b_cv[col];
        // lane's 4 acc values (r=0..3) are 4 consecutive W positions at channel col
        #pragma unroll
        for (int mi = 0; mi < 4; ++mi) {
            float4 v;
            v.x = acc[mi][0] + bias + res[mi][0];
            v.y = acc[mi][1] + bias + res[mi][1];
            v.z = acc[mi][2] + bias + res[mi][2];
            v.w = acc[mi][3] + bias + res[mi][3];
            *(float4*)(out + base + (long)col * 262144 + mi * 4096 + quad * 64) = v;
        }
    }
}

extern "C" void kernel_launch(void* const* d_in, const int* in_sizes, int n_in,
                              void* d_out, int out_size, void* d_ws, size_t ws_size,
                              hipStream_t stream) {
    (void)in_sizes; (void)n_in; (void)out_size;
    const float* x    = (const float*)d_in[0];
    const float* ln_g = (const float*)d_in[1];
    const float* ln_b = (const float*)d_in[2];
    const float* wq   = (const float*)d_in[3];
    const float* bq   = (const float*)d_in[4];
    const float* wo   = (const float*)d_in[5];
    const float* bo   = (const float*)d_in[6];
    const float* wc   = (const float*)d_in[7];
    const float* bc   = (const float*)d_in[8];
    if (d_ws && ws_size >= WS_NEED) {
        wconv_kernel<<<dim3(80), dim3(256), 0, stream>>>(wq, wo, wc, (ushort_t*)d_ws);
        wattn_kernel<true><<<dim3(8192), dim3(512), SMEM_BYTES, stream>>>(
            x, ln_g, ln_b, wq, bq, wo, bo, wc, bc, (const ushort_t*)d_ws, (float*)d_out);
    } else {
        wattn_kernel<false><<<dim3(8192), dim3(512), SMEM_BYTES, stream>>>(
            x, ln_g, ln_b, wq, bq, wo, bo, wc, bc, nullptr, (float*)d_out);
    }
}

// Round 4
// 770.721 us; speedup vs baseline: 1.1983x; 1.1983x over previous
//
#include <hip/hip_runtime.h>

typedef unsigned short ushort_t;
typedef __attribute__((ext_vector_type(8))) short short8;
typedef __attribute__((ext_vector_type(4))) short s16x4;
typedef __attribute__((ext_vector_type(4))) float f32x4;

#define LN_EPS 1e-5f

// LDS layout (bytes), time-multiplexed (barriers separate lifetimes):
//  P0-P1 : xw f32  [64][132]   @0      (33792)  XOR-swizzled cols (bits2-3 ^= row bits3-4)
//  P1-P2 : xn bf16 [64][136]   @33792  (17408, ends 51200)
//  P2-P3 : q  bf16 [4][64][32] @0      (16384)  XOR swz: d ^= (row&3)<<3
//          k  bf16 [4][64][32] @16384  (16384)  same swz
//  P2-P4 : vT bf16 [4][32][72] @32768  (18432, ends 51200)
//  P3-P4 : p  bf16 [4][64][64] @0      (32768)  XOR swz: col ^= (row&7)<<3   (aliases q+k exactly)
//  P4-P5 : o  bf16 [64][136]   @0      (17408)
//  P5-P6 : y  bf16 [64][136]   @17408  (17408)
// Peak = 51200 B -> 3 blocks/CU (hardware LDS limit). NOTE: launch_bounds stays
// (512,4) — (512,6) forced VGPR=40 and spilled ~0.9GB to scratch (R2 lesson).
#define XW_OFF 0
#define XN_OFF 33792
#define Q_OFF  0
#define K_OFF  16384
#define V_OFF  32768
#define P_OFF  0
#define O_OFF  0
#define Y_OFF  17408
#define SMEM_BYTES 51200

// bf16 weight workspace layout (shorts): wq [384*128] @0, wo @49152, wc @65536
#define WS_NEED 163840

// Manual RNE f32->bf16 (R1/R2-proven; no inline asm — R3's v_cvt_pk asm produced NaN).
static __device__ __forceinline__ ushort_t f2bf(float f) {
    union { float f; unsigned int u; } cv; cv.f = f;
    unsigned int x = cv.u + 0x7FFFu + ((cv.u >> 16) & 1u);   // RNE
    return (ushort_t)(x >> 16);
}
static __device__ __forceinline__ unsigned int pk2(float lo, float hi) {
    return (unsigned int)f2bf(lo) | ((unsigned int)f2bf(hi) << 16);
}

static __device__ __forceinline__ short8 loadw8(const float* p) {  // 8 f32 -> 8 bf16
    float4 a = *(const float4*)p;
    float4 b = *(const float4*)(p + 4);
    short8 r;
    r[0] = (short)f2bf(a.x); r[1] = (short)f2bf(a.y); r[2] = (short)f2bf(a.z); r[3] = (short)f2bf(a.w);
    r[4] = (short)f2bf(b.x); r[5] = (short)f2bf(b.y); r[6] = (short)f2bf(b.z); r[7] = (short)f2bf(b.w);
    return r;
}

// q/k LDS index: [h][row 0..63][d 0..31], stride 32 shorts (64B rows), bank-swizzled
static __device__ __forceinline__ int qk_i(int row, int d) {
    return row * 32 + (d ^ ((row & 3) << 3));
}
// p LDS index: [h][row 0..63][col 0..63], stride 64 shorts (128B rows), bank-swizzled
static __device__ __forceinline__ int p_i(int row, int col) {
    return row * 64 + (col ^ ((row & 7) << 3));
}

__global__ void wconv_kernel(const float* __restrict__ wq, const float* __restrict__ wo,
                             const float* __restrict__ wc, ushort_t* __restrict__ ws) {
    int i = blockIdx.x * 256 + threadIdx.x;   // 20480 threads x 4 floats
    float4 v;
    if (i < 12288)      v = ((const float4*)wq)[i];
    else if (i < 16384) v = ((const float4*)wo)[i - 12288];
    else                v = ((const float4*)wc)[i - 16384];
    s16x4 s;
    s[0] = (short)f2bf(v.x); s[1] = (short)f2bf(v.y);
    s[2] = (short)f2bf(v.z); s[3] = (short)f2bf(v.w);
    *(s16x4*)(ws + i * 4) = s;
}

template <bool PRE>
__global__ __launch_bounds__(512, 4) void wattn_kernel(
    const float* __restrict__ x,
    const float* __restrict__ ln_g,
    const float* __restrict__ ln_b,
    const float* __restrict__ w_qkv,   // [384][128] row-major (o,c)
    const float* __restrict__ b_qkv,
    const float* __restrict__ w_out,   // [128][128]
    const float* __restrict__ b_out,
    const float* __restrict__ w_cv,    // [128][128]
    const float* __restrict__ b_cv,
    const ushort_t* __restrict__ wbf,  // preconverted bf16 weights (if PRE)
    float* __restrict__ out)
{
    extern __shared__ char smem[];
    float*    xw  = (float*)(smem + XW_OFF);      // [64][132] f32, swizzled
    ushort_t* xn  = (ushort_t*)(smem + XN_OFF);   // [64][136]
    ushort_t* qls = (ushort_t*)(smem + Q_OFF);    // [4][64][32] swz
    ushort_t* kls = (ushort_t*)(smem + K_OFF);    // [4][64][32] swz
    ushort_t* vls = (ushort_t*)(smem + V_OFF);    // [4][32][72]
    ushort_t* pls = (ushort_t*)(smem + P_OFF);    // [4][64][64] swz, alias q/k
    ushort_t* ols = (ushort_t*)(smem + O_OFF);    // [64][136]   alias p
    ushort_t* yls = (ushort_t*)(smem + Y_OFF);    // [64][136]

    const int tid  = threadIdx.x;
    const int lane = tid & 63;
    const int wv   = tid >> 6;
    const int l15  = lane & 15;
    const int quad = lane >> 4;

    // XCD-aware bijective swizzle (8192 % 8 == 0)
    const int win = (blockIdx.x & 7) * 1024 + (blockIdx.x >> 3);
    const int bN  = win >> 12;
    const int dz  = (win >> 8) & 15;
    const int hy  = (win >> 4) & 15;
    const int wx  = win & 15;
    const long base = ((long)(bN * 128) * 64 + dz * 4) * 4096 + (long)(hy * 4) * 64 + wx * 4;

    // ---------- Phase 0: gather window -> xw[t][c^sw]  (float4 along W) ----------
    #pragma unroll
    for (int j = 0; j < 4; ++j) {
        int i  = tid + j * 512;      // [c:128][td:4][th:4]
        int c  = i >> 4;
        int td = (i >> 2) & 3;
        int th = i & 3;
        float4 v = *(const float4*)(x + base + (long)c * 262144 + td * 4096 + th * 64);
        int t0 = td * 16 + th * 4;
        int cs = c ^ ((th >> 1) << 2) ^ ((td & 1) << 3);   // == c ^ ((t>>3&1)<<2) ^ ((t>>4&1)<<3)
        xw[(t0 + 0) * 132 + cs] = v.x;
        xw[(t0 + 1) * 132 + cs] = v.y;
        xw[(t0 + 2) * 132 + cs] = v.z;
        xw[(t0 + 3) * 132 + cs] = v.w;
    }
    __syncthreads();

    // ---------- Phase 1: LayerNorm over channels -> xn ----------
    // 8 threads/token, channel groups c = 4p + 32m: read start-slot = (t+p) mod 8,
    // 2 lanes/slot = conflict-free (R1's p*16 layout was a 4-way read conflict).
    {
        int t = tid >> 3;            // token
        int p = tid & 7;
        int sw = (((t >> 3) & 1) << 2) | (((t >> 4) & 1) << 3);
        float vals[16];
        #pragma unroll
        for (int m = 0; m < 4; ++m) {
            float4 v = *(const float4*)(xw + t * 132 + ((4 * p + 32 * m) ^ sw));
            vals[4 * m + 0] = v.x; vals[4 * m + 1] = v.y;
            vals[4 * m + 2] = v.z; vals[4 * m + 3] = v.w;
        }
        float s = 0.f, ss = 0.f;
        #pragma unroll
        for (int j = 0; j < 16; ++j) { s += vals[j]; ss += vals[j] * vals[j]; }
        #pragma unroll
        for (int off = 1; off < 8; off <<= 1) {
            s  += __shfl_xor(s, off, 64);
            ss += __shfl_xor(ss, off, 64);
        }
        float mu   = s * 0.0078125f;
        float var  = ss * 0.0078125f - mu * mu;
        float rstd = rsqrtf(var + LN_EPS);
        #pragma unroll
        for (int m = 0; m < 4; ++m) {
            float4 g = *(const float4*)(ln_g + 4 * p + 32 * m);
            float4 b = *(const float4*)(ln_b + 4 * p + 32 * m);
            float e0 = (vals[4 * m + 0] - mu) * rstd * g.x + b.x;
            float e1 = (vals[4 * m + 1] - mu) * rstd * g.y + b.y;
            float e2 = (vals[4 * m + 2] - mu) * rstd * g.z + b.z;
            float e3 = (vals[4 * m + 3] - mu) * rstd * g.w + b.w;
            uint2 w; w.x = pk2(e0, e1); w.y = pk2(e2, e3);
            *(uint2*)(xn + t * 136 + 4 * p + 32 * m) = w;   // ds_write_b64
        }
    }
    __syncthreads();

    // ---------- Phase 2: QKV GEMM [64x128]@[128x384], wave owns 48 cols ----------
    {
        const int n_base = wv * 48;
        f32x4 acc[4][3];
        #pragma unroll
        for (int mi = 0; mi < 4; ++mi)
            #pragma unroll
            for (int ni = 0; ni < 3; ++ni) acc[mi][ni] = (f32x4){0.f, 0.f, 0.f, 0.f};
        #pragma unroll
        for (int ks = 0; ks < 4; ++ks) {
            int k0 = ks * 32 + quad * 8;
            short8 a[4], bfr[3];
            #pragma unroll
            for (int mi = 0; mi < 4; ++mi) a[mi] = *(const short8*)(xn + (mi * 16 + l15) * 136 + k0);
            #pragma unroll
            for (int ni = 0; ni < 3; ++ni) {
                if constexpr (PRE) bfr[ni] = *(const short8*)(wbf + (n_base + ni * 16 + l15) * 128 + k0);
                else               bfr[ni] = loadw8(w_qkv + (n_base + ni * 16 + l15) * 128 + k0);
            }
            #pragma unroll
            for (int ni = 0; ni < 3; ++ni)
                #pragma unroll
                for (int mi = 0; mi < 4; ++mi)
                    acc[mi][ni] = __builtin_amdgcn_mfma_f32_16x16x32_bf16(a[mi], bfr[ni], acc[mi][ni], 0, 0, 0);
        }
        __syncthreads();   // all waves done reading xn -> q/k/vT may overwrite xw/xn
        // epilogue: +bias, scatter q[h][t][d], k[h][t][d], vT[h][d][t]
        #pragma unroll
        for (int ni = 0; ni < 3; ++ni) {
            int col  = n_base + ni * 16 + l15;
            float bias = b_qkv[col];
            int sect = col >> 7;          // uniform per tile (16 | 128)
            int cc   = col & 127;
            int h = cc >> 5, d = cc & 31;
            if (sect == 2) {
                // vT rows consecutive in r -> pack 4 into one ds_write_b64
                #pragma unroll
                for (int mi = 0; mi < 4; ++mi) {
                    uint2 w;
                    w.x = pk2(acc[mi][ni][0] + bias, acc[mi][ni][1] + bias);
                    w.y = pk2(acc[mi][ni][2] + bias, acc[mi][ni][3] + bias);
                    *(uint2*)(vls + h * 2304 + d * 72 + mi * 16 + quad * 4) = w;
                }
            } else {
                ushort_t* dst = (sect == 0) ? qls : kls;
                #pragma unroll
                for (int mi = 0; mi < 4; ++mi)
                    #pragma unroll
                    for (int r = 0; r < 4; ++r) {
                        int row = mi * 16 + quad * 4 + r;
                        dst[h * 2048 + qk_i(row, d)] = f2bf(acc[mi][ni][r] + bias);
                    }
            }
        }
    }
    __syncthreads();

    // ---------- Phase 3/4: attention. wave w: head w>>1, q-rows (w&1)*32.. ----------
    {
        const int h  = wv >> 1;
        const int m0 = (wv & 1) * 32;
        const ushort_t* qh = qls + h * 2048;
        const ushort_t* kh = kls + h * 2048;
        f32x4 sc[2][4];
        #pragma unroll
        for (int mi = 0; mi < 2; ++mi)
            #pragma unroll
            for (int ni = 0; ni < 4; ++ni) sc[mi][ni] = (f32x4){0.f, 0.f, 0.f, 0.f};
        {
            short8 a[2], bfr[4];
            #pragma unroll
            for (int mi = 0; mi < 2; ++mi) a[mi] = *(const short8*)(qh + qk_i(m0 + mi * 16 + l15, quad * 8));
            #pragma unroll
            for (int ni = 0; ni < 4; ++ni) bfr[ni] = *(const short8*)(kh + qk_i(ni * 16 + l15, quad * 8));
            #pragma unroll
            for (int ni = 0; ni < 4; ++ni)
                #pragma unroll
                for (int mi = 0; mi < 2; ++mi)
                    sc[mi][ni] = __builtin_amdgcn_mfma_f32_16x16x32_bf16(a[mi], bfr[ni], sc[mi][ni], 0, 0, 0);
        }
        const float scale = 0.1767766952966369f;   // 1/sqrt(32)
        float pv[2][4][4];
        #pragma unroll
        for (int mi = 0; mi < 2; ++mi)
            #pragma unroll
            for (int r = 0; r < 4; ++r) {
                float v0 = sc[mi][0][r] * scale, v1 = sc[mi][1][r] * scale;
                float v2 = sc[mi][2][r] * scale, v3 = sc[mi][3][r] * scale;
                float mx = fmaxf(fmaxf(v0, v1), fmaxf(v2, v3));
                #pragma unroll
                for (int off = 1; off < 16; off <<= 1) mx = fmaxf(mx, __shfl_xor(mx, off, 64));
                float e0 = __expf(v0 - mx), e1 = __expf(v1 - mx), e2 = __expf(v2 - mx), e3 = __expf(v3 - mx);
                float sum = e0 + e1 + e2 + e3;
                #pragma unroll
                for (int off = 1; off < 16; off <<= 1) sum += __shfl_xor(sum, off, 64);
                float inv = 1.f / sum;
                pv[mi][0][r] = e0 * inv; pv[mi][1][r] = e1 * inv;
                pv[mi][2][r] = e2 * inv; pv[mi][3][r] = e3 * inv;
            }
        __syncthreads();   // all waves done with q/k -> safe to overlay p
        ushort_t* ph = pls + h * 4096;
        #pragma unroll
        for (int mi = 0; mi < 2; ++mi)
            #pragma unroll
            for (int ni = 0; ni < 4; ++ni)
                #pragma unroll
                for (int r = 0; r < 4; ++r)
                    ph[p_i(m0 + mi * 16 + quad * 4 + r, ni * 16 + l15)] = f2bf(pv[mi][ni][r]);
        __syncthreads();   // fence: p stores vs short8 reloads below
        // P @ V   [32x64]@[64x32]
        f32x4 oacc[2][2];
        #pragma unroll
        for (int mi = 0; mi < 2; ++mi)
            #pragma unroll
            for (int ni = 0; ni < 2; ++ni) oacc[mi][ni] = (f32x4){0.f, 0.f, 0.f, 0.f};
        #pragma unroll
        for (int kk = 0; kk < 2; ++kk) {
            int kq = kk * 32 + quad * 8;
            short8 a[2], bfr[2];
            #pragma unroll
            for (int mi = 0; mi < 2; ++mi) a[mi] = *(const short8*)(ph + p_i(m0 + mi * 16 + l15, kq));
            #pragma unroll
            for (int ni = 0; ni < 2; ++ni) bfr[ni] = *(const short8*)(vls + h * 2304 + (ni * 16 + l15) * 72 + kq);
            #pragma unroll
            for (int ni = 0; ni < 2; ++ni)
                #pragma unroll
                for (int mi = 0; mi < 2; ++mi)
                    oacc[mi][ni] = __builtin_amdgcn_mfma_f32_16x16x32_bf16(a[mi], bfr[ni], oacc[mi][ni], 0, 0, 0);
        }
        __syncthreads();   // all waves done reading p/vT -> o may overwrite p
        #pragma unroll
        for (int mi = 0; mi < 2; ++mi)
            #pragma unroll
            for (int ni = 0; ni < 2; ++ni)
                #pragma unroll
                for (int r = 0; r < 4; ++r)
                    ols[(m0 + mi * 16 + quad * 4 + r) * 136 + h * 32 + ni * 16 + l15] = f2bf(oacc[mi][ni][r]);
    }
    __syncthreads();

    // residual: lane (col, quad, mi) needs x[t0..t0+3] at channel col — one float4
    // along W per mi, identical mapping in P5/P6. L2-hot (fetched in P0).
    const int n0  = wv * 16;
    const int col = n0 + l15;
    float res[4][4];
    #pragma unroll
    for (int mi = 0; mi < 4; ++mi) {
        float4 r4 = *(const float4*)(x + base + (long)col * 262144 + mi * 4096 + quad * 64);
        res[mi][0] = r4.x; res[mi][1] = r4.y; res[mi][2] = r4.z; res[mi][3] = r4.w;
    }

    // ---------- Phase 5: out_proj [64x128]@[128x128] + attn residual -> y (bf16) ----------
    {
        f32x4 acc[4];
        #pragma unroll
        for (int mi = 0; mi < 4; ++mi) acc[mi] = (f32x4){0.f, 0.f, 0.f, 0.f};
        #pragma unroll
        for (int ks = 0; ks < 4; ++ks) {
            int k0 = ks * 32 + quad * 8;
            short8 bfr;
            if constexpr (PRE) bfr = *(const short8*)(wbf + 49152 + (n0 + l15) * 128 + k0);
            else               bfr = loadw8(w_out + (n0 + l15) * 128 + k0);
            #pragma unroll
            for (int mi = 0; mi < 4; ++mi) {
                short8 a = *(const short8*)(ols + (mi * 16 + l15) * 136 + k0);
                acc[mi] = __builtin_amdgcn_mfma_f32_16x16x32_bf16(a, bfr, acc[mi], 0, 0, 0);
            }
        }
        float bias = b_out[col];
        #pragma unroll
        for (int mi = 0; mi < 4; ++mi)
            #pragma unroll
            for (int r = 0; r < 4; ++r) {
                int row = mi * 16 + quad * 4 + r;
                yls[row * 136 + col] = f2bf(acc[mi][r] + bias + res[mi][r]);
            }
    }
    __syncthreads();

    // ---------- Phase 6: conv [64x128]@[128x128] + input residual -> direct global store ----------
    {
        f32x4 acc[4];
        #pragma unroll
        for (int mi = 0; mi < 4; ++mi) acc[mi] = (f32x4){0.f, 0.f, 0.f, 0.f};
        #pragma unroll
        for (int ks = 0; ks < 4; ++ks) {
            int k0 = ks * 32 + quad * 8;
            short8 bfr;
            if constexpr (PRE) bfr = *(const short8*)(wbf + 65536 + (n0 + l15) * 128 + k0);
            else               bfr = loadw8(w_cv + (n0 + l15) * 128 + k0);
            #pragma unroll
            for (int mi = 0; mi < 4; ++mi) {
                short8 a = *(const short8*)(yls + (mi * 16 + l15) * 136 + k0);
                acc[mi] = __builtin_amdgcn_mfma_f32_16x16x32_bf16(a, bfr, acc[mi], 0, 0, 0);
            }
        }
        float bias = b_cv[col];
        // lane's 4 acc values (r=0..3) are 4 consecutive W positions at channel col
        #pragma unroll
        for (int mi = 0; mi < 4; ++mi) {
            float4 v;
            v.x = acc[mi][0] + bias + res[mi][0];
            v.y = acc[mi][1] + bias + res[mi][1];
            v.z = acc[mi][2] + bias + res[mi][2];
            v.w = acc[mi][3] + bias + res[mi][3];
            *(float4*)(out + base + (long)col * 262144 + mi * 4096 + quad * 64) = v;
        }
    }
}

extern "C" void kernel_launch(void* const* d_in, const int* in_sizes, int n_in,
                              void* d_out, int out_size, void* d_ws, size_t ws_size,
                              hipStream_t stream) {
    (void)in_sizes; (void)n_in; (void)out_size;
    const float* x    = (const float*)d_in[0];
    const float* ln_g = (const float*)d_in[1];
    const float* ln_b = (const float*)d_in[2];
    const float* wq   = (const float*)d_in[3];
    const float* bq   = (const float*)d_in[4];
    const float* wo   = (const float*)d_in[5];
    const float* bo   = (const float*)d_in[6];
    const float* wc   = (const float*)d_in[7];
    const float* bc   = (const float*)d_in[8];
    if (d_ws && ws_size >= WS_NEED) {
        wconv_kernel<<<dim3(80), dim3(256), 0, stream>>>(wq, wo, wc, (ushort_t*)d_ws);
        wattn_kernel<true><<<dim3(8192), dim3(512), SMEM_BYTES, stream>>>(
            x, ln_g, ln_b, wq, bq, wo, bo, wc, bc, (const ushort_t*)d_ws, (float*)d_out);
    } else {
        wattn_kernel<false><<<dim3(8192), dim3(512), SMEM_BYTES, stream>>>(
            x, ln_g, ln_b, wq, bq, wo, bo, wc, bc, nullptr, (float*)d_out);
    }
}